// Round 3
// baseline (171.245 us; speedup 1.0000x reference)
//
#include <hip/hip_runtime.h>
#include <stdint.h>
#include <stddef.h>

// Actor_DeepSet: rows = 131072 (= 16384 batches x 8 agents), OBS=64, HIDDEN=128, OUT=16.
// R3: no X staging (per-lane global halo loads with &63 wrap), H2 aliases Hc via
//     deferred layer-2 writes => LDS 33792 B => 4 blocks/CU (16 waves/CU).
//     Biases folded into MFMA accumulator init; /8 folded into w1o/b1o.

typedef __attribute__((ext_vector_type(8))) short short8;       // 8 x bf16 (4 VGPR)
typedef __attribute__((ext_vector_type(4))) float floatx4;      // MFMA C/D
typedef __attribute__((ext_vector_type(4))) float float4v;

static __device__ __forceinline__ unsigned int cvtpk(float lo, float hi) {
    unsigned int r;
    asm("v_cvt_pk_bf16_f32 %0, %1, %2" : "=v"(r) : "v"(lo), "v"(hi));
    return r;
}
static __device__ __forceinline__ unsigned short f2bf(float f) {
    return (unsigned short)cvtpk(f, f);
}

static __device__ __forceinline__ floatx4 mfma16(short8 a, short8 b, floatx4 c) {
    return __builtin_amdgcn_mfma_f32_16x16x32_bf16(a, b, c, 0, 0, 0);
}

// ---- prologue: convert all weights to bf16 into d_ws (w1o pre-scaled by 1/8) ----
// ws layout (ushort elems): w1[8192] | w1o[8192] | w2[32768] | wv[2048]  (total 51200)
__global__ void cvt_weights(const float* __restrict__ w1, const float* __restrict__ w1o,
                            const float* __restrict__ w2, const float* __restrict__ wv,
                            unsigned short* __restrict__ ws) {
    int i = blockIdx.x * 256 + threadIdx.x;   // grid sized exactly 51200/256 = 200 blocks
    float v;
    if (i < 8192)       v = w1[i];
    else if (i < 16384) v = w1o[i - 8192] * 0.125f;   // fold the /8 (relu pos-homog.)
    else if (i < 49152) v = w2[i - 16384];
    else                v = wv[i - 49152];
    ws[i] = f2bf(v);
}

__launch_bounds__(256, 4)
__global__ void actor_fused(const float* __restrict__ X,          // [131072][64]
                            const unsigned short* __restrict__ ws,
                            const float* __restrict__ b1p,        // [128]
                            const float* __restrict__ b1op,       // [128]
                            const float* __restrict__ b2p,        // [128]
                            const float* __restrict__ bvp,        // [16]
                            float* __restrict__ out) {            // [131072][16]
    // LDS 33792 B: Hc[64][264]; H2[64][136] ALIASES it (all Hc reads complete
    // before first H2 write — enforced by bar-B). Strides ≡ 4 dwords mod 32.
    __shared__ __align__(16) unsigned char smem[33792];
    unsigned short (*Hc)[264] = (unsigned short (*)[264])smem;    // 33792 B
    unsigned short (*H2)[136] = (unsigned short (*)[136])smem;    // 17408 B (alias)

    const int tid  = threadIdx.x;
    const int wid  = tid >> 6;         // 0..3
    const int lane = tid & 63;
    const int l15  = lane & 15;
    const int l16  = lane >> 4;        // 0..3
    const long R0  = (long)blockIdx.x * 64;

    const unsigned short* w1b  = ws;
    const unsigned short* w1ob = ws + 8192;
    const unsigned short* w2b  = ws + 16384;
    const unsigned short* wvb  = ws + 49152;

    // --- per-lane A-window loads straight from global (halo, &63 wraps the roll) ---
    // lane holds X row (16*wid+l15), f32 elems [l16*8, l16*8+16) and [32+l16*8, +16) mod 64
    const float* xp = X + (R0 + 16 * wid + l15) * 64;
    float4v a0 = *(const float4v*)(xp + l16 * 8);
    float4v a1 = *(const float4v*)(xp + l16 * 8 + 4);
    float4v a2 = *(const float4v*)(xp + l16 * 8 + 8);
    float4v a3 = *(const float4v*)(xp + l16 * 8 + 12);
    float4v c0 = *(const float4v*)(xp + ((32 + l16 * 8) & 63));
    float4v c1 = *(const float4v*)(xp + ((36 + l16 * 8) & 63));
    float4v c2 = *(const float4v*)(xp + ((40 + l16 * 8) & 63));
    float4v c3 = *(const float4v*)(xp + ((44 + l16 * 8) & 63));

    // --- w1o B-fragments + scaled bias (latency overlaps window loads) ---
    short8 bo[8][2];
    float b1o_r[8];
    #pragma unroll
    for (int n = 0; n < 8; ++n) {
        const int h = n * 16 + l15;
        bo[n][0] = *(const short8*)(w1ob + h * 64 + l16 * 8);
        bo[n][1] = *(const short8*)(w1ob + h * 64 + 32 + l16 * 8);
        b1o_r[n] = 0.125f * b1op[h];
    }

    unsigned int u0[8], u1[8];
    u0[0] = cvtpk(a0.x, a0.y); u0[1] = cvtpk(a0.z, a0.w);
    u0[2] = cvtpk(a1.x, a1.y); u0[3] = cvtpk(a1.z, a1.w);
    u0[4] = cvtpk(a2.x, a2.y); u0[5] = cvtpk(a2.z, a2.w);
    u0[6] = cvtpk(a3.x, a3.y); u0[7] = cvtpk(a3.z, a3.w);
    u1[0] = cvtpk(c0.x, c0.y); u1[1] = cvtpk(c0.z, c0.w);
    u1[2] = cvtpk(c1.x, c1.y); u1[3] = cvtpk(c1.z, c1.w);
    u1[4] = cvtpk(c2.x, c2.y); u1[5] = cvtpk(c2.z, c2.w);
    u1[6] = cvtpk(c3.x, c3.y); u1[7] = cvtpk(c3.z, c3.w);

    // --- 8 rolled passes: pass kx computes, for batches {2*wid, 2*wid+1},
    //     S_{a=kx}[h] = sum_{j=1..7} relu( roll_{kx+1}(x_j) . (w1o/8)[h] + b1o/8 ) ---
    #pragma unroll
    for (int kx = 0; kx < 8; ++kx) {
        const int kk = kx + 1;          // roll amount, compile-time per unrolled iter
        const int c  = kk >> 1;
        union { unsigned int u[4]; short8 v; } A0, A1;
        #pragma unroll
        for (int d = 0; d < 4; ++d) {
            if (kk & 1) {
                A0.u[d] = (u0[d + c] >> 16) | (u0[d + c + 1] << 16);
                A1.u[d] = (u1[d + c] >> 16) | (u1[d + c + 1] << 16);
            } else {
                A0.u[d] = u0[d + c];
                A1.u[d] = u1[d + c];
            }
        }
        floatx4 acc[8];
        #pragma unroll
        for (int n = 0; n < 8; ++n) {
            const float b = b1o_r[n];
            acc[n] = (floatx4){b, b, b, b};          // bias folded into C-init
        }
        #pragma unroll
        for (int n = 0; n < 8; ++n) {
            acc[n] = mfma16(A0.v, bo[n][0], acc[n]);
            acc[n] = mfma16(A1.v, bo[n][1], acc[n]);
        }
        // epilogue: relu, sum rows 1..7 of each 8-row (=one batch) group
        #pragma unroll
        for (int n = 0; n < 8; ++n) {
            float r0 = fmaxf(acc[n].x, 0.f);          // C row = l16*4+0
            float r1 = fmaxf(acc[n].y, 0.f);
            float r2 = fmaxf(acc[n].z, 0.f);
            float r3 = fmaxf(acc[n].w, 0.f);
            float t = r1 + r2 + r3 + (((l16 & 1) != 0) ? r0 : 0.f);  // drop j==0 rows
            float s = t + __shfl_xor(t, 16, 64);      // combine row-halves of each batch
            if ((lane & 16) == 0) {                   // l16==0 -> batch0, l16==2 -> batch1
                int row = 16 * wid + ((lane >> 5) << 3) + kx;   // agent i = kx
                Hc[row][128 + n * 16 + l15] = f2bf(s);
            }
        }
    }

    // --- h1 pass (roll 0, weights w1) ---
    {
        short8 b1fr[8][2];
        float b1_r[8];
        #pragma unroll
        for (int n = 0; n < 8; ++n) {
            const int h = n * 16 + l15;
            b1fr[n][0] = *(const short8*)(w1b + h * 64 + l16 * 8);
            b1fr[n][1] = *(const short8*)(w1b + h * 64 + 32 + l16 * 8);
            b1_r[n]    = b1p[h];
        }
        union { unsigned int u[4]; short8 v; } A0, A1;
        #pragma unroll
        for (int d = 0; d < 4; ++d) { A0.u[d] = u0[d]; A1.u[d] = u1[d]; }
        floatx4 acc[8];
        #pragma unroll
        for (int n = 0; n < 8; ++n) {
            const float b = b1_r[n];
            acc[n] = (floatx4){b, b, b, b};
        }
        #pragma unroll
        for (int n = 0; n < 8; ++n) {
            acc[n] = mfma16(A0.v, b1fr[n][0], acc[n]);
            acc[n] = mfma16(A1.v, b1fr[n][1], acc[n]);
        }
        #pragma unroll
        for (int n = 0; n < 8; ++n) {
            #pragma unroll
            for (int r = 0; r < 4; ++r) {
                int row = 16 * wid + l16 * 4 + r;
                Hc[row][n * 16 + l15] = f2bf(fmaxf(acc[n][r], 0.f));
            }
        }
    }

    // --- layer 2: h2 = relu(Hcat @ w2^T + b2). wave owns cols 32*wid..32*wid+31.
    //     H2 writes DEFERRED past bar-B so H2 may alias Hc. ---
    short8 w2f[2][8];
    floatx4 acc2[4][2];
    #pragma unroll
    for (int n = 0; n < 2; ++n) {
        const int h = wid * 32 + n * 16 + l15;
        const float b = b2p[h];
        #pragma unroll
        for (int mt = 0; mt < 4; ++mt) acc2[mt][n] = (floatx4){b, b, b, b};
        #pragma unroll
        for (int s = 0; s < 8; ++s)
            w2f[n][s] = *(const short8*)(w2b + (size_t)h * 256 + s * 32 + l16 * 8);
    }
    __syncthreads();   // bar-A: Hc complete

    #pragma unroll
    for (int mt = 0; mt < 4; ++mt) {
        #pragma unroll
        for (int s = 0; s < 8; ++s) {
            short8 a = *(const short8*)(&Hc[mt * 16 + l15][s * 32 + l16 * 8]);
            acc2[mt][0] = mfma16(a, w2f[0][s], acc2[mt][0]);
            acc2[mt][1] = mfma16(a, w2f[1][s], acc2[mt][1]);
        }
    }

    // final-layer B-frags (global, hoistable by scheduler)
    short8 wvf[4];
    #pragma unroll
    for (int s = 0; s < 4; ++s)
        wvf[s] = *(const short8*)(wvb + l15 * 128 + s * 32 + l16 * 8);
    const float bv_r = bvp[l15];

    __syncthreads();   // bar-B: all Hc reads done -> safe to overwrite (H2 alias)

    #pragma unroll
    for (int mt = 0; mt < 4; ++mt) {
        #pragma unroll
        for (int n = 0; n < 2; ++n) {
            #pragma unroll
            for (int r = 0; r < 4; ++r) {
                int row = mt * 16 + l16 * 4 + r;
                H2[row][wid * 32 + n * 16 + l15] = f2bf(fmaxf(acc2[mt][n][r], 0.f));
            }
        }
    }
    __syncthreads();   // bar-C: H2 complete

    // --- final layer: out = h2 @ wv^T + bv. wave owns rows 16*wid..+15 ---
    {
        floatx4 acc4 = (floatx4){bv_r, bv_r, bv_r, bv_r};
        #pragma unroll
        for (int s = 0; s < 4; ++s) {
            short8 a = *(const short8*)(&H2[wid * 16 + l15][s * 32 + l16 * 8]);
            acc4 = mfma16(a, wvf[s], acc4);
        }
        #pragma unroll
        for (int r = 0; r < 4; ++r) {
            long row = R0 + 16 * wid + l16 * 4 + r;
            out[row * 16 + l15] = acc4[r];
        }
    }
}

extern "C" void kernel_launch(void* const* d_in, const int* in_sizes, int n_in,
                              void* d_out, int out_size, void* d_ws, size_t ws_size,
                              hipStream_t stream) {
    (void)n_in; (void)out_size; (void)ws_size;
    const float* X   = (const float*)d_in[0];
    const float* w1  = (const float*)d_in[1];
    const float* b1  = (const float*)d_in[2];
    const float* w1o = (const float*)d_in[3];
    const float* b1o = (const float*)d_in[4];
    const float* w2  = (const float*)d_in[5];
    const float* b2  = (const float*)d_in[6];
    const float* wv  = (const float*)d_in[7];
    const float* bv  = (const float*)d_in[8];
    float* out = (float*)d_out;
    unsigned short* ws = (unsigned short*)d_ws;

    // weights -> bf16 (51200 elems, 200*256 threads exactly)
    cvt_weights<<<200, 256, 0, stream>>>(w1, w1o, w2, wv, ws);

    const int rows   = in_sizes[0] / 64;   // 131072
    const int blocks = rows / 64;          // 2048
    actor_fused<<<blocks, 256, 0, stream>>>(X, ws, b1, b1o, b2, bv, out);
}